// Round 2
// baseline (322.979 us; speedup 1.0000x reference)
//
#include <hip/hip_runtime.h>

#define NB 32
#define H 384
#define W 640
#define NC 128
#define FH 96        // H/4
#define FWID 160     // W/4
#define BORDER 30
#define PTHRESH 0.015f
#define TOPK 2000
#define HW (H * W)   // 245760
#define NWAVE 4      // waves scanning rows concurrently (256 threads)
#define NXIT 10      // 640 / 64 ballot iterations per row
#define PTILE 64     // points per gather block
#define NTILE ((TOPK + PTILE - 1) / PTILE)  // 32 (tile 31 has 16 pts)

// r_shape may arrive as int32 (harness-converted) or raw int64. Under int64
// little-endian layout, word [2b+1] is the high word of element b (384/640)
// and is therefore 0 -> unambiguous discriminator.
__device__ inline void load_rshape(const int* p32, int b, int* rs0, int* rs1) {
  const int a = p32[2 * b];
  const int c = p32[2 * b + 1];
  if (c == 0) {  // int64 storage
    const long long* p64 = (const long long*)p32;
    *rs0 = (int)p64[2 * b];
    *rs1 = (int)p64[2 * b + 1];
  } else {  // int32 storage
    *rs0 = a;
    *rs1 = c;
  }
}

// ---------------------------------------------------------------------------
// Fused kernel: each 256-thread block owns one 64-point output tile of one
// batch. Phase 1 re-runs the ordered ballot compaction over prob rows (same
// scan as the verified compact_kernel: 4 waves scan 4 rows, ballots kept in
// registers, LDS count exchange, prefix, replay) but extracts ONLY positions
// in [k0, k0+npts) straight into LDS — no global idx round-trip, no separate
// launch. At ~571 hits/row every block finishes in ONE 4-row chunk; the 4
// prob rows are shared by all 32 tiles of the batch (L2-hot).
// Phase 2 is the unchanged tiled bilinear gather.
// ---------------------------------------------------------------------------
__global__ __launch_bounds__(256) void fused_kernel(
    const float* __restrict__ prob, const int* __restrict__ rsp,
    const float* __restrict__ featmap, const float* __restrict__ ratio,
    float* __restrict__ pts, float* __restrict__ des) {
  const int tile = blockIdx.x;  // 0..NTILE-1
  const int b = blockIdx.y;     // 0..NB-1
  const int k0 = tile * PTILE;
  const int npts = (TOPK - k0) < PTILE ? (TOPK - k0) : PTILE;
  const int kend = k0 + npts;
  const int pk0 = b * TOPK + k0;
  const int tid = threadIdx.x;
  const int lane = tid & 63;
  const int wv = tid >> 6;  // 0..3

  int rs0, rs1;
  load_rshape(rsp, b, &rs0, &rs1);
  const int ymax = rs0 - BORDER;  // valid rows: [BORDER, ymax)
  const int xmax = rs1 - BORDER;  // valid cols: [BORDER, xmax)
  const float* pb = prob + (size_t)b * HW;
  const unsigned long long ltmask = (1ull << lane) - 1ull;

  __shared__ int s_cnt[NWAVE];
  __shared__ int s_idx[PTILE];
  __shared__ float s_tile[NC][PTILE + 1];

  if (tid < PTILE) s_idx[tid] = HW;  // sentinel: unfilled -> pts/des = 0
  __syncthreads();

  // ---- Phase 1: ordered compaction, window [k0, kend) only ----
  int chunk_base = 0;
  for (int row0 = BORDER; row0 < ymax && chunk_base < kend; row0 += NWAVE) {
    const int r = row0 + wv;
    unsigned long long mbs[NXIT];
    int cnt = 0;
    if (r < ymax) {
      const float* rowp = pb + r * W;
#pragma unroll
      for (int t = 0; t < NXIT; ++t) {
        const int x = t * 64 + lane;
        const bool m = (x >= BORDER) && (x < xmax) && (rowp[x] > PTHRESH);
        mbs[t] = __ballot(m);
        cnt += __popcll(mbs[t]);
      }
    } else {
#pragma unroll
      for (int t = 0; t < NXIT; ++t) mbs[t] = 0;
    }
    if (lane == 0) s_cnt[wv] = cnt;
    __syncthreads();
    int row_start = chunk_base;
    int total = 0;
#pragma unroll
    for (int j = 0; j < NWAVE; ++j) {
      const int cj = s_cnt[j];
      if (j < wv) row_start += cj;
      total += cj;
    }
    // replay ballots; keep only ranks falling inside this block's window
    if (cnt > 0 && row_start < kend && row_start + cnt > k0) {
      int rank = row_start;
      const int ibase = r * W;
#pragma unroll
      for (int t = 0; t < NXIT; ++t) {
        const unsigned long long mb = mbs[t];
        const bool m = (mb >> lane) & 1ull;
        const int pos = rank + __popcll(mb & ltmask);
        if (m && pos >= k0 && pos < kend)
          s_idx[pos - k0] = ibase + t * 64 + lane;
        rank += __popcll(mb);
      }
    }
    chunk_base += total;
    __syncthreads();  // s_cnt reuse + publishes s_idx writes of this chunk
  }
  // loop is uniform across the block; trailing __syncthreads ordered s_idx.

  // ---- Phase 2: tiled bilinear gather (unchanged from verified kernel) ----
  const int idx = s_idx[lane];
  const bool valid = (unsigned)idx < (unsigned)HW;
  const int ic = valid ? idx : 0;
  const int y = ic / W;
  const int x = ic - y * W;
  const int x0 = x >> 2;
  const int y0 = y >> 2;
  const float fx = (float)(x & 3) * 0.25f;
  const float fy = (float)(y & 3) * 0.25f;
  const float gx = 1.0f - fx, gy = 1.0f - fy;
  float wa = gx * gy, wb = gx * fy, wc = fx * gy, wd = fx * fy;
  if (!valid) wa = wb = wc = wd = 0.0f;  // -> v = 0 exactly

  const float* fp0 = featmap + (((size_t)b * NC) * FH + y0) * FWID + x0;
#pragma unroll 4
  for (int j = 0; j < NC / 4; ++j) {
    const int c = wv * (NC / 4) + j;
    const float* fp = fp0 + (size_t)c * (FH * FWID);
    const float Ia = fp[0];
    const float Ic = fp[1];
    const float Ib = fp[FWID];
    const float Id = fp[FWID + 1];
    s_tile[c][lane] = Ia * wa + Ib * wb + Ic * wc + Id * wd;
  }

  if (wv == 0 && lane < npts) {
    const float r = ratio[b];
    pts[(size_t)(pk0 + lane) * 2 + 0] = valid ? (float)x / r : 0.0f;
    pts[(size_t)(pk0 + lane) * 2 + 1] = valid ? (float)y / r : 0.0f;
  }

  __syncthreads();

  // coalesced write-out: thread t -> channel (t&127), points step 2
  float* db = des + (size_t)pk0 * NC;
  const int c = tid & 127;
  for (int k = tid >> 7; k < npts; k += 2)
    db[(size_t)k * NC + c] = s_tile[c][k];
}

extern "C" void kernel_launch(void* const* d_in, const int* in_sizes, int n_in,
                              void* d_out, int out_size, void* d_ws,
                              size_t ws_size, hipStream_t stream) {
  const float* prob = (const float*)d_in[0];     // (32,1,384,640) f32
  const float* featmap = (const float*)d_in[1];  // (32,128,96,160) f32
  const float* ratio = (const float*)d_in[2];    // (32,1) f32
  const int* r_shape = (const int*)d_in[3];      // (32,2) int (dtype sniffed)

  float* pts = (float*)d_out;                // (32,2000,2)
  float* des = pts + (size_t)NB * TOPK * 2;  // (32,2000,128)

  dim3 grid(NTILE, NB);
  fused_kernel<<<grid, 256, 0, stream>>>(prob, r_shape, featmap, ratio, pts,
                                         des);
}